// Round 9
// baseline (118.508 us; speedup 1.0000x reference)
//
#include <hip/hip_runtime.h>
#include <math.h>

#define DIM    4096      // 2^12
#define LAYERS 4
#define NB     1024      // batch
#define SSLOT  17        // padded v2f slots per 16-amp slice (bank spread)

typedef float v2f __attribute__((ext_vector_type(2)));

__device__ __forceinline__ v2f cmul(v2f a, v2f b) {
    return (v2f){a.x * b.x - a.y * b.y, a.x * b.y + a.y * b.x};
}
__device__ __forceinline__ float fxor(float f, unsigned m) {
    return __uint_as_float(__float_as_uint(f) ^ m);
}

// ---- verified in-register SU(2) gate (Ry*Rx fused) on reg bit G ----
// P1=(cc,cs), P2=(ss,sc); 8 v_pk ops per pair.
template<int G>
__device__ __forceinline__ void gate_pk(v2f (&x)[16], v2f P1, v2f P2) {
#pragma unroll
    for (int p = 0; p < 8; ++p) {
        const int j0 = ((p >> G) << (G + 1)) | (p & ((1 << G) - 1));
        const int j1 = j0 | (1 << G);
        const v2f x0 = x[j0], x1 = x[j1];
        v2f t, u;
        asm("v_pk_mul_f32 %0, %1, %2 op_sel:[1,1] op_sel_hi:[1,0] neg_hi:[1,0]"
            : "=v"(t) : "v"(P2), "v"(x1));
        asm("v_pk_fma_f32 %0, %1, %2, %0 op_sel:[1,0,0] op_sel_hi:[1,1,1] neg_lo:[1,0,0] neg_hi:[1,0,0]"
            : "+v"(t) : "v"(P1), "v"(x1));
        asm("v_pk_fma_f32 %0, %1, %2, %0 op_sel:[0,1,0] op_sel_hi:[0,0,1] neg_lo:[1,0,0]"
            : "+v"(t) : "v"(P2), "v"(x0));
        asm("v_pk_fma_f32 %0, %1, %2, %0 op_sel:[0,0,0] op_sel_hi:[0,1,1]"
            : "+v"(t) : "v"(P1), "v"(x0));
        asm("v_pk_mul_f32 %0, %1, %2 op_sel:[0,1] op_sel_hi:[0,0] neg_hi:[1,0]"
            : "=v"(u) : "v"(P2), "v"(x1));
        asm("v_pk_fma_f32 %0, %1, %2, %0 op_sel:[0,0,0] op_sel_hi:[0,1,1]"
            : "+v"(u) : "v"(P1), "v"(x1));
        asm("v_pk_fma_f32 %0, %1, %2, %0 op_sel:[1,1,0] op_sel_hi:[1,0,1] neg_hi:[1,0,0]"
            : "+v"(u) : "v"(P2), "v"(x0));
        asm("v_pk_fma_f32 %0, %1, %2, %0 op_sel:[1,0,0] op_sel_hi:[1,1,1]"
            : "+v"(u) : "v"(P1), "v"(x0));
        x[j0] = t; x[j1] = u;
    }
}

// ---- distributed gate: partner amp lives in another lane, fetched by F ----
// Per-side form (derived from the pair form): y = cc*x + ssS*(ix) + csS*p - sc*(ip)
// with ssS = sigma*ss, csS = -sigma*cs, sigma = +1 on the 0-side lane.
// P1=(cc,csS), P2=(ssS,sc). 4 pk ops + 2 cross-lane fetches per amp.
template<typename F>
__device__ __forceinline__ void gate_lane(v2f (&x)[16], v2f P1, v2f P2, F fetch) {
#pragma unroll
    for (int j = 0; j < 16; ++j) {
        v2f p;
        p.x = fetch(x[j].x);
        p.y = fetch(x[j].y);
        v2f t;
        asm("v_pk_mul_f32 %0, %1, %2 op_sel:[1,1] op_sel_hi:[1,0] neg_hi:[1,0]"
            : "=v"(t) : "v"(P2), "v"(p));                 // ( sc*pi, -sc*pr)
        asm("v_pk_fma_f32 %0, %1, %2, %0 op_sel:[1,0,0] op_sel_hi:[1,1,1]"
            : "+v"(t) : "v"(P1), "v"(p));                 // + (csS*pr, csS*pi)
        asm("v_pk_fma_f32 %0, %1, %2, %0 op_sel:[0,1,0] op_sel_hi:[0,0,1] neg_lo:[1,0,0]"
            : "+v"(t) : "v"(P2), "v"(x[j]));              // + (-ssS*xi, ssS*xr)
        asm("v_pk_fma_f32 %0, %1, %2, %0 op_sel:[0,0,0] op_sel_hi:[0,1,1]"
            : "+v"(t) : "v"(P1), "v"(x[j]));              // + (cc*xr, cc*xi)
        x[j] = t;
    }
}

// complex MAC acc (+)= M (*) v  (M=(re,im) packed)
__device__ __forceinline__ v2f cmac_init(v2f M, v2f v) {
    v2f acc;
    asm("v_pk_mul_f32 %0, %1, %2 op_sel:[0,0] op_sel_hi:[0,1]"
        : "=v"(acc) : "v"(M), "v"(v));                    // (a*vr, a*vi)
    asm("v_pk_fma_f32 %0, %1, %2, %0 op_sel:[1,1,0] op_sel_hi:[1,0,1] neg_lo:[1,0,0]"
        : "+v"(acc) : "v"(M), "v"(v));                    // + (-b*vi, b*vr)
    return acc;
}
__device__ __forceinline__ void cmac(v2f& acc, v2f M, v2f v) {
    asm("v_pk_fma_f32 %0, %1, %2, %0 op_sel:[0,0,0] op_sel_hi:[0,1,1]"
        : "+v"(acc) : "v"(M), "v"(v));
    asm("v_pk_fma_f32 %0, %1, %2, %0 op_sel:[1,1,0] op_sel_hi:[1,0,1] neg_lo:[1,0,0]"
        : "+v"(acc) : "v"(M), "v"(v));
}

// cross-lane fetch functors
struct FDpp1 { __device__ float operator()(float f) const {           // lane^1
    return __int_as_float(__builtin_amdgcn_update_dpp(0, __float_as_int(f), 0xB1, 0xF, 0xF, false)); } };
struct FDpp2 { __device__ float operator()(float f) const {           // lane^2
    return __int_as_float(__builtin_amdgcn_update_dpp(0, __float_as_int(f), 0x4E, 0xF, 0xF, false)); } };
template<int IMM> struct FSwz { __device__ float operator()(float f) const {
    return __int_as_float(__builtin_amdgcn_ds_swizzle(__float_as_int(f), IMM)); } };
struct FBp { int a; __device__ float operator()(float f) const {      // lane^32
    return __int_as_float(__builtin_amdgcn_ds_bpermute(a, __float_as_int(f))); } };

// Fixed mapping: amp = t*16 + r. reg bits 3:0 = qubits 8..11; lane bits 5:0 =
// qubits 7..2 (lane^2^k partners via DPP/swizzle/bpermute, no LDS storage);
// wave bits (t>>6) = qubits 0,1 -> one fused 4x4 staged LDS exchange per layer.
__global__ __launch_bounds__(256, 4) void qddpm_kernel(
    const float* __restrict__ in_re,
    const float* __restrict__ in_im,
    const float* __restrict__ params,
    const float* __restrict__ uu,
    float* __restrict__ out)
{
    __shared__ v2f    S[256 * SSLOT];  // 34.8 KB staging (slice slot = t*17+r)
    __shared__ float4 gco[48];         // per-gate (cc, cs, ss, sc)
    __shared__ float  sprob[16];

    const int b = blockIdx.x;
    const int t = threadIdx.x;
    const int l = t & 63;
    const float uval = uu[b];

    v2f x[16];
    // ---- global -> regs: thread t holds amps 16t..16t+15 (contig float4) ----
    {
        const float4* re4 = (const float4*)(in_re + (size_t)b * DIM + t * 16);
        const float4* im4 = (const float4*)(in_im + (size_t)b * DIM + t * 16);
#pragma unroll
        for (int q = 0; q < 4; ++q) {
            const float4 vr = re4[q];
            const float4 vi = im4[q];
            x[4 * q + 0] = (v2f){vr.x, vi.x};
            x[4 * q + 1] = (v2f){vr.y, vi.y};
            x[4 * q + 2] = (v2f){vr.z, vi.z};
            x[4 * q + 3] = (v2f){vr.w, vi.w};
        }
    }
    // ---- gate coeffs, computed redundantly by every wave (no barrier) ----
    if (l < 48) {
        const int lay = l / 12, q = l - lay * 12;
        float c1, s1, c2, s2;
        sincosf(params[lay * 24 + q] * 0.5f, &s1, &c1);
        sincosf(params[lay * 24 + 12 + q] * 0.5f, &s2, &c2);
        gco[l] = make_float4(c1 * c2, c1 * s2, s1 * s2, s1 * c2); // (cc,cs,ss,sc)
    }
    // CZ sign mask for this thread's amps (i = 16t + r)
    int smask = 0;
#pragma unroll
    for (int j = 0; j < 16; ++j) {
        const int i = t * 16 + j;
        smask |= (__popc(i & (i >> 1) & 0x7FF) & 1) << j;
    }
    const int sbase = t * SSLOT;
    const int bp32  = (l ^ 32) << 2;

#pragma unroll 1
    for (int lay = 0; lay < LAYERS; ++lay) {
        const int gb = lay * 12;

        // ---- qubits 0,1 (wave bits): fused 4x4 via staged LDS exchange ----
        if (lay) __syncthreads();      // prior layer's reads done before overwrite
#pragma unroll
        for (int r = 0; r < 16; ++r) S[sbase + r] = x[r];
        __syncthreads();
        {
            const float4 g0 = gco[gb + 0], g1 = gco[gb + 1];
            const int i0 = (t >> 7) & 1, i1 = (t >> 6) & 1;
            // row entries of U_q0: ea = diag (U00 or U11), eb = off-diag
            const v2f ea = (v2f){g0.x, i0 ? -g0.z : g0.z};
            const v2f eb = (v2f){i0 ? g0.y : -g0.y, -g0.w};
            const v2f fa = (v2f){g1.x, i1 ? -g1.z : g1.z};
            const v2f fb = (v2f){i1 ? g1.y : -g1.y, -g1.w};
            const v2f Mo = cmul(ea, fa);   // own quadrant
            const v2f M1 = cmul(ea, fb);   // partner t^64  (qubit1 flip)
            const v2f M2 = cmul(eb, fa);   // partner t^128 (qubit0 flip)
            const v2f M3 = cmul(eb, fb);   // partner t^192
            const int p1 = (t ^ 64) * SSLOT, p2 = (t ^ 128) * SSLOT, p3 = (t ^ 192) * SSLOT;
#pragma unroll
            for (int r = 0; r < 16; ++r) {
                const v2f q1 = S[p1 + r], q2 = S[p2 + r], q3 = S[p3 + r];
                v2f acc = cmac_init(Mo, x[r]);
                cmac(acc, M1, q1);
                cmac(acc, M2, q2);
                cmac(acc, M3, q3);
                x[r] = acc;
            }
        }

        // ---- qubits 7..2 (lane bits 0..5): cross-lane gates ----
        { const float4 c = gco[gb + 7]; const unsigned n = (unsigned)(l & 1) << 31;
          gate_lane(x, (v2f){c.x, fxor(c.y, n ^ 0x80000000u)}, (v2f){fxor(c.z, n), c.w}, FDpp1{}); }
        { const float4 c = gco[gb + 6]; const unsigned n = (unsigned)((l >> 1) & 1) << 31;
          gate_lane(x, (v2f){c.x, fxor(c.y, n ^ 0x80000000u)}, (v2f){fxor(c.z, n), c.w}, FDpp2{}); }
        { const float4 c = gco[gb + 5]; const unsigned n = (unsigned)((l >> 2) & 1) << 31;
          gate_lane(x, (v2f){c.x, fxor(c.y, n ^ 0x80000000u)}, (v2f){fxor(c.z, n), c.w}, FSwz<0x101F>{}); }
        { const float4 c = gco[gb + 4]; const unsigned n = (unsigned)((l >> 3) & 1) << 31;
          gate_lane(x, (v2f){c.x, fxor(c.y, n ^ 0x80000000u)}, (v2f){fxor(c.z, n), c.w}, FSwz<0x201F>{}); }
        { const float4 c = gco[gb + 3]; const unsigned n = (unsigned)((l >> 4) & 1) << 31;
          gate_lane(x, (v2f){c.x, fxor(c.y, n ^ 0x80000000u)}, (v2f){fxor(c.z, n), c.w}, FSwz<0x401F>{}); }
        { const float4 c = gco[gb + 2]; const unsigned n = (unsigned)((l >> 5) & 1) << 31;
          gate_lane(x, (v2f){c.x, fxor(c.y, n ^ 0x80000000u)}, (v2f){fxor(c.z, n), c.w}, FBp{bp32}); }

        // ---- qubits 8..11 (reg bits): in-register gates ----
        { const float4 c = gco[gb + 11]; gate_pk<0>(x, (v2f){c.x, c.y}, (v2f){c.z, c.w}); }
        { const float4 c = gco[gb + 10]; gate_pk<1>(x, (v2f){c.x, c.y}, (v2f){c.z, c.w}); }
        { const float4 c = gco[gb +  9]; gate_pk<2>(x, (v2f){c.x, c.y}, (v2f){c.z, c.w}); }
        { const float4 c = gco[gb +  8]; gate_pk<3>(x, (v2f){c.x, c.y}, (v2f){c.z, c.w}); }

        // ---- CZ diagonal ----
#pragma unroll
        for (int r = 0; r < 16; ++r) {
            const unsigned sg = (unsigned)((smask >> r) & 1) << 31;
            x[r].x = fxor(x[r].x, sg);
            x[r].y = fxor(x[r].y, sg);
        }
    }

    // ---- final state to LDS + ancilla probs (outcome of amp 16t+r is t>>4) ----
    __syncthreads();                   // protect S vs last exchange's reads
#pragma unroll
    for (int r = 0; r < 16; ++r) S[sbase + r] = x[r];
    {
        v2f acc2 = (v2f){0.0f, 0.0f};
#pragma unroll
        for (int r = 0; r < 16; ++r) acc2 += x[r] * x[r];
        float partial = acc2.x + acc2.y;
#pragma unroll
        for (int o = 8; o > 0; o >>= 1)
            partial += __shfl_down(partial, o, 16);
        if ((t & 15) == 0) sprob[t >> 4] = partial;
    }
    __syncthreads();

    // ---- redundant per-thread inverse-CDF sample + output [B, 256, 2] ----
    {
        float cdf[16];
        float a = 0.0f;
#pragma unroll
        for (int i = 0; i < 16; ++i) { a += sprob[i]; cdf[i] = a; }
        const float thresh = uval * a;
        int m = 0;
#pragma unroll
        for (int i = 15; i >= 0; --i) { if (cdf[i] >= thresh) m = i; }
        const float rn = 1.0f / sqrtf(sprob[m]);
        // amp m*256 + t lives in slice t' = 16m + (t>>4), reg r = t&15
        const v2f amp = S[272 * m + SSLOT * (t >> 4) + (t & 15)];
        ((float2*)out)[(size_t)b * 256 + t] = make_float2(amp.x * rn, amp.y * rn);
    }
}

extern "C" void kernel_launch(void* const* d_in, const int* in_sizes, int n_in,
                              void* d_out, int out_size, void* d_ws, size_t ws_size,
                              hipStream_t stream) {
    const float* in_re  = (const float*)d_in[0];
    const float* in_im  = (const float*)d_in[1];
    const float* params = (const float*)d_in[2];
    const float* u      = (const float*)d_in[3];
    float* out = (float*)d_out;
    qddpm_kernel<<<NB, 256, 0, stream>>>(in_re, in_im, params, u, out);
}

// Round 10
// 111.528 us; speedup vs baseline: 1.0626x; 1.0626x over previous
//
#include <hip/hip_runtime.h>
#include <math.h>

#define DIM    4096      // 2^12
#define LAYERS 4
#define NB     1024      // batch
#define SPAD   4608      // phys(i) = i + 2*(i>>4); max 4095+510 = 4605

typedef float v2f __attribute__((ext_vector_type(2)));

// Fused (Ry*Rx) SU(2) gate on local bit G of a 16-amp register block, complex
// interleaved (lo=re, hi=im). Coefficients packed: P1=(cc,cs), P2=(ss,sc).
// 8 v_pk_*_f32 per pair; swaps/negs via op_sel / neg modifiers.
template<int G>
__device__ __forceinline__ void gate_pk(v2f (&x)[16], v2f P1, v2f P2) {
#pragma unroll
    for (int p = 0; p < 8; ++p) {
        const int j0 = ((p >> G) << (G + 1)) | (p & ((1 << G) - 1));
        const int j1 = j0 | (1 << G);
        const v2f x0 = x[j0], x1 = x[j1];
        v2f t, u;
        asm("v_pk_mul_f32 %0, %1, %2 op_sel:[1,1] op_sel_hi:[1,0] neg_hi:[1,0]"
            : "=v"(t) : "v"(P2), "v"(x1));
        asm("v_pk_fma_f32 %0, %1, %2, %0 op_sel:[1,0,0] op_sel_hi:[1,1,1] neg_lo:[1,0,0] neg_hi:[1,0,0]"
            : "+v"(t) : "v"(P1), "v"(x1));
        asm("v_pk_fma_f32 %0, %1, %2, %0 op_sel:[0,1,0] op_sel_hi:[0,0,1] neg_lo:[1,0,0]"
            : "+v"(t) : "v"(P2), "v"(x0));
        asm("v_pk_fma_f32 %0, %1, %2, %0 op_sel:[0,0,0] op_sel_hi:[0,1,1]"
            : "+v"(t) : "v"(P1), "v"(x0));
        asm("v_pk_mul_f32 %0, %1, %2 op_sel:[0,1] op_sel_hi:[0,0] neg_hi:[1,0]"
            : "=v"(u) : "v"(P2), "v"(x1));
        asm("v_pk_fma_f32 %0, %1, %2, %0 op_sel:[0,0,0] op_sel_hi:[0,1,1]"
            : "+v"(u) : "v"(P1), "v"(x1));
        asm("v_pk_fma_f32 %0, %1, %2, %0 op_sel:[1,1,0] op_sel_hi:[1,0,1] neg_hi:[1,0,0]"
            : "+v"(u) : "v"(P2), "v"(x0));
        asm("v_pk_fma_f32 %0, %1, %2, %0 op_sel:[1,0,0] op_sel_hi:[1,1,1]"
            : "+v"(u) : "v"(P1), "v"(x0));
        x[j0] = t; x[j1] = u;
    }
}

__device__ __forceinline__ void apply4(v2f (&x)[16], const float4* gco, int base) {
    float4 c;
    c = gco[base + 3]; gate_pk<0>(x, (v2f){c.x, c.y}, (v2f){c.z, c.w});
    c = gco[base + 2]; gate_pk<1>(x, (v2f){c.x, c.y}, (v2f){c.z, c.w});
    c = gco[base + 1]; gate_pk<2>(x, (v2f){c.x, c.y}, (v2f){c.z, c.w});
    c = gco[base + 0]; gate_pk<3>(x, (v2f){c.x, c.y}, (v2f){c.z, c.w});
}

__device__ __forceinline__ void applyCZ(v2f (&x)[16], const int (&sw)[16]) {
#pragma unroll
    for (int j = 0; j < 16; ++j) {
        x[j].x = __uint_as_float(__float_as_uint(x[j].x) ^ sw[j]);
        x[j].y = __uint_as_float(__float_as_uint(x[j].y) ^ sw[j]);
    }
}

// ---- pass load/store helpers (padded layout phys(i) = i + 2*(i>>4)) ----
__device__ __forceinline__ void loadA(v2f (&x)[16], const v2f* Sp, int baseA) {
#pragma unroll
    for (int j = 0; j < 16; ++j) x[j] = Sp[baseA + 288 * j];
}
__device__ __forceinline__ void storeA(const v2f (&x)[16], v2f* Sp, int baseA) {
#pragma unroll
    for (int j = 0; j < 16; ++j) Sp[baseA + 288 * j] = x[j];
}
__device__ __forceinline__ void loadB(v2f (&x)[16], const v2f* Sp, int baseB) {
#pragma unroll
    for (int j = 0; j < 16; ++j) x[j] = Sp[baseB + 18 * j];
}
__device__ __forceinline__ void storeB(const v2f (&x)[16], v2f* Sp, int baseB) {
#pragma unroll
    for (int j = 0; j < 16; ++j) Sp[baseB + 18 * j] = x[j];
}
__device__ __forceinline__ void loadC(v2f (&x)[16], const v2f* Sp, int baseC) {
    const float4* src = (const float4*)(Sp + baseC);   // 16B aligned (t*144)
#pragma unroll
    for (int q = 0; q < 8; ++q) {
        const float4 v = src[q];
        x[2 * q]     = (v2f){v.x, v.y};
        x[2 * q + 1] = (v2f){v.z, v.w};
    }
}
__device__ __forceinline__ void storeC(const v2f (&x)[16], v2f* Sp, int baseC) {
    float4* dst = (float4*)(Sp + baseC);
#pragma unroll
    for (int q = 0; q < 8; ++q)
        dst[q] = make_float4(x[2 * q].x, x[2 * q].y, x[2 * q + 1].x, x[2 * q + 1].y);
}
__device__ __forceinline__ void gloadC(v2f (&x)[16], const float* re, const float* im) {
    const float4* re4 = (const float4*)re;
    const float4* im4 = (const float4*)im;
#pragma unroll
    for (int q = 0; q < 4; ++q) {
        const float4 vr = re4[q];
        const float4 vi = im4[q];
        x[4 * q + 0] = (v2f){vr.x, vi.x};
        x[4 * q + 1] = (v2f){vr.y, vi.y};
        x[4 * q + 2] = (v2f){vr.z, vi.z};
        x[4 * q + 3] = (v2f){vr.w, vi.w};
    }
}
__device__ __forceinline__ void probs16(const v2f (&x)[16], float* spr, int t) {
    v2f a2 = (v2f){0.0f, 0.0f};
#pragma unroll
    for (int j = 0; j < 16; ++j) a2 += x[j] * x[j];
    float p = a2.x + a2.y;
#pragma unroll
    for (int o = 8; o > 0; o >>= 1) p += __shfl_down(p, o, 16);
    if ((t & 15) == 0) spr[t >> 4] = p;
}
__device__ __forceinline__ void emit(const v2f* Sp, const float* spr, float uval,
                                     float2* o2, int t, int baseA) {
    float cdf[16];
    float a = 0.0f;
#pragma unroll
    for (int i = 0; i < 16; ++i) { a += spr[i]; cdf[i] = a; }
    const float th = uval * a;
    int m = 0;
#pragma unroll
    for (int i = 15; i >= 0; --i) { if (cdf[i] >= th) m = i; }
    const float rn = 1.0f / sqrtf(spr[m]);
    const v2f amp = Sp[baseA + 288 * m];     // phys(m*256 + t), A-pattern
    o2[t] = make_float2(amp.x * rn, amp.y * rn);
}

// TWO samples per 256-thread block (x = sample 2b, y = sample 2b+1).
// Palindrome schedule per sample: C0 B0 | A0·Z·A1 | B1 C1·Z·C2 B2 | A2·Z·A3 |
// B3 C3·Z. B/C passes are wave-local (no barrier); A passes are inter-wave.
// The two samples' passes are interleaved so each sample's LDS phase hides
// under the other's 1024-cycle pk phase (in-wave software pipelining); 5
// barriers serve both samples. LDS 2x36KB -> 2 blocks/CU (8 waves/CU).
__global__ __launch_bounds__(256, 2) void qddpm_kernel(
    const float* __restrict__ in_re,
    const float* __restrict__ in_im,
    const float* __restrict__ params,
    const float* __restrict__ uu,
    float* __restrict__ out)
{
    __shared__ v2f    S0[SPAD], S1[SPAD];
    __shared__ float4 gco[48];
    __shared__ float  sprob[2][16];

    const int b = blockIdx.x;            // 0..511, samples 2b and 2b+1
    const int t = threadIdx.x;
    const int l = t & 63;
    const float u0 = uu[2 * b], u1 = uu[2 * b + 1];

    const int baseA = t + 2 * (t >> 4);
    const int baseB = (t >> 4) * 288 + (t & 15);
    const int baseC = t * 18;

    v2f x[16], y[16];

    // ---- both samples' global loads issued up front (C pattern) ----
    gloadC(x, in_re + (size_t)(2 * b) * DIM + t * 16,
              in_im + (size_t)(2 * b) * DIM + t * 16);
    gloadC(y, in_re + (size_t)(2 * b + 1) * DIM + t * 16,
              in_im + (size_t)(2 * b + 1) * DIM + t * 16);

    // ---- gate coeffs, redundantly per wave (no barrier; overlaps loads) ----
    if (l < 48) {
        const int lay = l / 12, q = l - lay * 12;
        float c1, s1, c2, s2;
        sincosf(params[lay * 24 + q] * 0.5f, &s1, &c1);
        sincosf(params[lay * 24 + 12 + q] * 0.5f, &s2, &c2);
        gco[l] = make_float4(c1 * c2, c1 * s2, s1 * s2, s1 * c2); // (cc,cs,ss,sc)
    }

    // CZ sign-bit xor words for A- and C-partition amps
    int swA[16], swC[16];
#pragma unroll
    for (int j = 0; j < 16; ++j) {
        const int iC = t * 16 + j;
        swC[j] = (__popc(iC & (iC >> 1) & 0x7FF) & 1) << 31;
        const int iA = j * 256 + t;
        swA[j] = (__popc(iA & (iA >> 1) & 0x7FF) & 1) << 31;
    }

    // ---- region 0: C0 | B0 (wave-local), both samples interleaved ----
    apply4(x, gco, 8);  storeC(x, S0, baseC);
    apply4(y, gco, 8);  storeC(y, S1, baseC);
    loadB(x, S0, baseB); apply4(x, gco, 4);  storeB(x, S0, baseB);
    loadB(y, S1, baseB); apply4(y, gco, 4);  storeB(y, S1, baseB);
    __syncthreads();                     // (1) B -> A

    // ---- region 1: A0 + CZ0 + A1 ----
    loadA(x, S0, baseA); loadA(y, S1, baseA);
    apply4(x, gco, 0);  applyCZ(x, swA); apply4(x, gco, 12); storeA(x, S0, baseA);
    apply4(y, gco, 0);  applyCZ(y, swA); apply4(y, gco, 12); storeA(y, S1, baseA);
    __syncthreads();                     // (2) A -> B

    // ---- region 2: B1 | C1+CZ1+C2 | B2 (all wave-local) ----
    loadB(x, S0, baseB); loadB(y, S1, baseB);
    apply4(x, gco, 16); storeB(x, S0, baseB);
    apply4(y, gco, 16); storeB(y, S1, baseB);
    loadC(x, S0, baseC);
    apply4(x, gco, 20); applyCZ(x, swC); apply4(x, gco, 32); storeC(x, S0, baseC);
    loadC(y, S1, baseC);
    apply4(y, gco, 20); applyCZ(y, swC); apply4(y, gco, 32); storeC(y, S1, baseC);
    loadB(x, S0, baseB); apply4(x, gco, 28); storeB(x, S0, baseB);
    loadB(y, S1, baseB); apply4(y, gco, 28); storeB(y, S1, baseB);
    __syncthreads();                     // (3) B -> A

    // ---- region 3: A2 + CZ2 + A3 ----
    loadA(x, S0, baseA); loadA(y, S1, baseA);
    apply4(x, gco, 24); applyCZ(x, swA); apply4(x, gco, 36); storeA(x, S0, baseA);
    apply4(y, gco, 24); applyCZ(y, swA); apply4(y, gco, 36); storeA(y, S1, baseA);
    __syncthreads();                     // (4) A -> B

    // ---- region 4: B3 | C3+CZ3 + probs (wave-local) ----
    loadB(x, S0, baseB); loadB(y, S1, baseB);
    apply4(x, gco, 40); storeB(x, S0, baseB);
    apply4(y, gco, 40); storeB(y, S1, baseB);
    loadC(x, S0, baseC);
    apply4(x, gco, 44); applyCZ(x, swC);
    probs16(x, sprob[0], t);
    storeC(x, S0, baseC);
    loadC(y, S1, baseC);
    apply4(y, gco, 44); applyCZ(y, swC);
    probs16(y, sprob[1], t);
    storeC(y, S1, baseC);
    __syncthreads();                     // (5) S + sprob ready block-wide

    // ---- epilogue: inverse-CDF sample + output for both samples ----
    float2* o2 = (float2*)out;
    emit(S0, sprob[0], u0, o2 + (size_t)(2 * b) * 256,     t, baseA);
    emit(S1, sprob[1], u1, o2 + (size_t)(2 * b + 1) * 256, t, baseA);
}

extern "C" void kernel_launch(void* const* d_in, const int* in_sizes, int n_in,
                              void* d_out, int out_size, void* d_ws, size_t ws_size,
                              hipStream_t stream) {
    const float* in_re  = (const float*)d_in[0];
    const float* in_im  = (const float*)d_in[1];
    const float* params = (const float*)d_in[2];
    const float* u      = (const float*)d_in[3];
    float* out = (float*)d_out;
    qddpm_kernel<<<NB / 2, 256, 0, stream>>>(in_re, in_im, params, u, out);
}